// Round 10
// baseline (239.401 us; speedup 1.0000x reference)
//
#include <hip/hip_runtime.h>
#include <hip/hip_bf16.h>
#include <math.h>

#define NEGS 0.2f
#define BSH 9                 // bucket shift: 512 nodes per bucket
#define TS 4096               // edges per partition tile

typedef __attribute__((ext_vector_type(8))) short bf16x8;
typedef __attribute__((ext_vector_type(8))) unsigned short u16x8;
typedef __attribute__((ext_vector_type(4))) float f32x4;

__device__ __forceinline__ unsigned short f2bf(float f) {
  __hip_bfloat16 h = __float2bfloat16(f);   // compiler emits v_cvt_pk_bf16_f32
  unsigned short u;
  __builtin_memcpy(&u, &h, 2);
  return u;
}
__device__ __forceinline__ float bf2f(unsigned short u) {
  return __uint_as_float((unsigned)u << 16);
}
__device__ __forceinline__ unsigned packbf(float lo, float hi) {
  return (unsigned)f2bf(lo) | ((unsigned)f2bf(hi) << 16);
}

// ---------------- device bodies (block-range fused) -------------------------

// W1 -> bf16 fragment-ordered [ck][ks][kgrp][col][8k], zero-padded
__device__ __forceinline__ void dev_wcvt(const float* __restrict__ W1,
                                         unsigned short* __restrict__ Wb,
                                         int K, int Kp, int blk) {
  int t = blk * 256 + threadIdx.x;
  if (t >= Kp * 64) return;
  int kg = t >> 6, c = t & 63;
  float f = (kg < K) ? W1[(size_t)kg * 64 + c] : 0.f;
  size_t off = ((size_t)((kg >> 5) * 4 + ((kg >> 3) & 3)) * 512) + c * 8 + (kg & 7);
  Wb[off] = f2bf(f);
}

__device__ __forceinline__ void dev_thist(const int* __restrict__ ei,
                                          int* __restrict__ hist,
                                          int E, int NB, int tile) {
  __shared__ int lh[256];
  const int t = threadIdx.x;
  lh[t] = 0;
  __syncthreads();
  const int e0 = tile * TS;
#pragma unroll
  for (int j = 0; j < TS / 256; ++j) {
    int e = e0 + j * 256 + t;
    if (e < E) atomicAdd(&lh[ei[E + e] >> BSH], 1);
  }
  __syncthreads();
  if (t < NB) hist[tile * NB + t] = lh[t];
}

__device__ __forceinline__ void dev_bscan1(const int* __restrict__ hist,
                                           int* __restrict__ off_rel,
                                           int* __restrict__ total,
                                           int NT, int NB, int b) {
  __shared__ int sh[256];
  const int t = threadIdx.x;
  int t0 = 2 * t, t1 = 2 * t + 1;
  int v0 = (t0 < NT) ? hist[t0 * NB + b] : 0;
  int v1 = (t1 < NT) ? hist[t1 * NB + b] : 0;
  int ps = v0 + v1;
  sh[t] = ps;
  __syncthreads();
  for (int off = 1; off < 256; off <<= 1) {
    int v = (t >= off) ? sh[t - off] : 0;
    __syncthreads();
    sh[t] += v;
    __syncthreads();
  }
  int excl = sh[t] - ps;
  if (t0 < NT) off_rel[t0 * NB + b] = excl;
  if (t1 < NT) off_rel[t1 * NB + b] = excl + v0;
  if (t == 255) total[b] = sh[255];
}

__device__ __forceinline__ void dev_pscatter(const int* __restrict__ ei,
                                             const int* __restrict__ off_rel,
                                             const int* __restrict__ total,
                                             unsigned* __restrict__ pairs,
                                             int E, int NB, int tile) {
  __shared__ int cur[256];
  __shared__ int sb[256];
  const int t = threadIdx.x;
  int v = (t < NB) ? total[t] : 0;
  sb[t] = v;
  __syncthreads();
  for (int off = 1; off < 256; off <<= 1) {
    int x = (t >= off) ? sb[t - off] : 0;
    __syncthreads();
    sb[t] += x;
    __syncthreads();
  }
  if (t < NB) cur[t] = (sb[t] - v) + off_rel[tile * NB + t];
  __syncthreads();
  const int e0 = tile * TS;
#pragma unroll
  for (int j = 0; j < TS / 256; ++j) {
    int e = e0 + j * 256 + t;
    if (e < E) {
      int s = ei[e], d = ei[E + e];
      int pos = atomicAdd(&cur[d >> BSH], 1);
      pairs[pos] = ((unsigned)(d & ((1 << BSH) - 1)) << 23) | (unsigned)s;
    }
  }
}

__device__ __forceinline__ void dev_bcsr(const unsigned* __restrict__ pairs,
                                         const int* __restrict__ total,
                                         int* __restrict__ rowptr,
                                         int* __restrict__ col,
                                         int Nn, int E, int NB, int b) {
  __shared__ int cnt[1 << BSH];
  __shared__ int cu[1 << BSH];
  __shared__ int sh[256];
  __shared__ int P0, P1;
  const int t = threadIdx.x;
  const int d0 = b << BSH;
  const int dn = min(1 << BSH, Nn - d0);
  {
    int v = (t < NB) ? total[t] : 0;
    sh[t] = v;
    __syncthreads();
    for (int off = 1; off < 256; off <<= 1) {
      int x = (t >= off) ? sh[t - off] : 0;
      __syncthreads();
      sh[t] += x;
      __syncthreads();
    }
    if (t == b) { P0 = sh[t] - v; P1 = sh[t]; }
    __syncthreads();
  }
  const int p0 = P0, p1 = P1;
  const int rpb = p0 + d0;
  cnt[2 * t] = (2 * t < dn) ? 1 : 0;
  cnt[2 * t + 1] = (2 * t + 1 < dn) ? 1 : 0;
  __syncthreads();
  for (int i = p0 + t; i < p1; i += 256) atomicAdd(&cnt[pairs[i] >> 23], 1);
  __syncthreads();
  int a0 = cnt[2 * t], a1 = cnt[2 * t + 1];
  int ps = a0 + a1;
  sh[t] = ps;
  __syncthreads();
  for (int off = 1; off < 256; off <<= 1) {
    int v = (t >= off) ? sh[t - off] : 0;
    __syncthreads();
    sh[t] += v;
    __syncthreads();
  }
  int excl = sh[t] - ps;
#pragma unroll
  for (int u = 0; u < 2; ++u) {
    int i = 2 * t + u;
    int ex = (u == 0) ? excl : excl + a0;
    if (i < dn) {
      rowptr[d0 + i] = rpb + ex;
      col[rpb + ex] = d0 + i;   // self-loop
      cu[i] = ex + 1;
    }
  }
  if (b == NB - 1 && t == 0) rowptr[Nn] = E + Nn;
  __syncthreads();
  for (int i = p0 + t; i < p1; i += 256) {
    unsigned p = pairs[i];
    int pos = atomicAdd(&cu[p >> 23], 1);
    col[rpb + pos] = (int)(p & 0x7fffffu);
  }
}

// GEMM1 slice (no LDS) + fused prep1 epilogue
__device__ __forceinline__ void dev_gemm(const float* __restrict__ A,
                                         const unsigned short* __restrict__ Wb,
                                         unsigned short* __restrict__ C,
                                         const float* __restrict__ a1s,
                                         const float* __restrict__ a1d,
                                         float* __restrict__ ssrc,
                                         float* __restrict__ sdst,
                                         int M, int K, int nck, int rowblk) {
  const int tid = threadIdx.x;
  const int lane = tid & 63;
  const int w = tid >> 6;
  const int r15 = lane & 15;
  const int kgrp = lane >> 4;
  const int bm = rowblk * 64;
  const int row = bm + w * 16 + r15;
  const float* Ar = A + (size_t)(row < M ? row : (M - 1)) * K;

  f32x4 acc[4] = {};

  for (int ck = 0; ck < nck; ++ck) {
#pragma unroll
    for (int ks = 0; ks < 2; ++ks) {
      const int k0 = ck * 64 + ks * 32 + kgrp * 8;
      bf16x8 af;
      if (ck < nck - 1) {
        const float4* g = (const float4*)(Ar + k0);
        float4 f0 = g[0], f1 = g[1];
        unsigned pk[4] = { packbf(f0.x, f0.y), packbf(f0.z, f0.w),
                           packbf(f1.x, f1.y), packbf(f1.z, f1.w) };
        af = *(bf16x8*)pk;
      } else {
        float f[8];
#pragma unroll
        for (int j = 0; j < 8; ++j) {
          int kk = k0 + j;
          f[j] = (kk < K) ? Ar[kk] : 0.f;
        }
        unsigned pk[4];
#pragma unroll
        for (int j = 0; j < 4; ++j) pk[j] = packbf(f[2 * j], f[2 * j + 1]);
        af = *(bf16x8*)pk;
      }
      const unsigned short* bb =
          Wb + ((size_t)((ck * 2 + ks) * 4 + kgrp) * 512) + r15 * 8;
      bf16x8 bf4[4];
#pragma unroll
      for (int nc = 0; nc < 4; ++nc)
        bf4[nc] = *(const bf16x8*)(bb + nc * 128);
#pragma unroll
      for (int nc = 0; nc < 4; ++nc)
        acc[nc] = __builtin_amdgcn_mfma_f32_16x16x32_bf16(af, bf4[nc], acc[nc], 0, 0, 0);
    }
  }
  // epilogue: bf16 C write + fused attention-half dots (prep1)
  float av[4], dv[4];
#pragma unroll
  for (int nc = 0; nc < 4; ++nc) {
    av[nc] = a1s[nc * 16 + r15];
    dv[nc] = a1d[nc * 16 + r15];
  }
#pragma unroll
  for (int j = 0; j < 4; ++j) {
    int grow = bm + w * 16 + kgrp * 4 + j;
    bool liv = grow < M;
#pragma unroll
    for (int nc = 0; nc < 4; ++nc) {
      if (liv) C[(size_t)grow * 64 + nc * 16 + r15] = f2bf(acc[nc][j]);
      // head h = nc*2 + (r15>>3); reduce over the 8 lanes of the r15-subgroup
      float ss = acc[nc][j] * av[nc];
      float sd = acc[nc][j] * dv[nc];
      ss += __shfl_xor(ss, 1); ss += __shfl_xor(ss, 2); ss += __shfl_xor(ss, 4);
      sd += __shfl_xor(sd, 1); sd += __shfl_xor(sd, 2); sd += __shfl_xor(sd, 4);
      if ((r15 & 7) == 0 && liv) {
        int h = nc * 2 + (r15 >> 3);
        ssrc[grow * 8 + h] = ss;
        sdst[grow * 8 + h] = sd;
      }
    }
  }
}

// ---------------- fused launch wrappers -------------------------------------
__global__ __launch_bounds__(256) void k_A(const float* __restrict__ W1,
                                           unsigned short* __restrict__ Wb,
                                           int K, int Kp,
                                           const int* __restrict__ ei,
                                           int* __restrict__ hist,
                                           int E, int NB, int WCB) {
  int b = blockIdx.x;
  if (b < WCB) dev_wcvt(W1, Wb, K, Kp, b);
  else dev_thist(ei, hist, E, NB, b - WCB);
}

__global__ __launch_bounds__(256) void k_B1(const int* __restrict__ hist,
                                            int* __restrict__ off_rel,
                                            int* __restrict__ total,
                                            int NT, int NB,
                                            const float* __restrict__ A,
                                            const unsigned short* __restrict__ Wb,
                                            unsigned short* __restrict__ C,
                                            const float* __restrict__ a1s,
                                            const float* __restrict__ a1d,
                                            float* __restrict__ ssrc,
                                            float* __restrict__ sdst,
                                            int M, int K, int nck, int R0) {
  int b = blockIdx.x;
  if (b < NB) dev_bscan1(hist, off_rel, total, NT, NB, b);
  else dev_gemm(A, Wb, C, a1s, a1d, ssrc, sdst, M, K, nck, b - NB + R0);
}

__global__ __launch_bounds__(256) void k_B2(const int* __restrict__ ei,
                                            const int* __restrict__ off_rel,
                                            const int* __restrict__ total,
                                            unsigned* __restrict__ pairs,
                                            int E, int NB, int NT,
                                            const float* __restrict__ A,
                                            const unsigned short* __restrict__ Wb,
                                            unsigned short* __restrict__ C,
                                            const float* __restrict__ a1s,
                                            const float* __restrict__ a1d,
                                            float* __restrict__ ssrc,
                                            float* __restrict__ sdst,
                                            int M, int K, int nck, int R0) {
  int b = blockIdx.x;
  if (b < NT) dev_pscatter(ei, off_rel, total, pairs, E, NB, b);
  else dev_gemm(A, Wb, C, a1s, a1d, ssrc, sdst, M, K, nck, b - NT + R0);
}

__global__ __launch_bounds__(256) void k_B3(const unsigned* __restrict__ pairs,
                                            const int* __restrict__ total,
                                            int* __restrict__ rowptr,
                                            int* __restrict__ col,
                                            int Nn, int E, int NB,
                                            const float* __restrict__ A,
                                            const unsigned short* __restrict__ Wb,
                                            unsigned short* __restrict__ C,
                                            const float* __restrict__ a1s,
                                            const float* __restrict__ a1d,
                                            float* __restrict__ ssrc,
                                            float* __restrict__ sdst,
                                            int M, int K, int nck, int R0) {
  int b = blockIdx.x;
  if (b < NB) dev_bcsr(pairs, total, rowptr, col, Nn, E, NB, b);
  else dev_gemm(A, Wb, C, a1s, a1d, ssrc, sdst, M, K, nck, b - NB + R0);
}

// ------- layer-1 aggregate: 8 edges/iter, lane = slot(8) x head(8) ----------
__global__ __launch_bounds__(256) void k_agg1(const int* __restrict__ rowptr,
                                              const int* __restrict__ col,
                                              const float* __restrict__ ssrc,
                                              const float* __restrict__ sdst,
                                              const unsigned short* __restrict__ xwb,
                                              const float* __restrict__ b1,
                                              float* __restrict__ h1, int Nn) {
  int wid = (blockIdx.x * 256 + threadIdx.x) >> 6;
  if (wid >= Nn) return;
  int lane = threadIdx.x & 63;
  int slot = lane >> 3;
  int chg = lane & 7;
  float sd = sdst[wid * 8 + chg];
  int start = rowptr[wid], end = rowptr[wid + 1];
  float den = 0.f;
  float acc[8] = {};
  for (int it = start; it < end; it += 8) {
    int idx = it + slot;
    bool ok = idx < end;
    int s = col[ok ? idx : start];
    u16x8 pv = *(const u16x8*)(xwb + (size_t)s * 64 + chg * 8);
    float v = ssrc[s * 8 + chg] + sd;
    v = v > 0.f ? v : NEGS * v;
    float p = ok ? __expf(v) : 0.f;
    den += p;
#pragma unroll
    for (int j = 0; j < 8; ++j) acc[j] = fmaf(p, bf2f(pv[j]), acc[j]);
  }
#pragma unroll
  for (int off = 8; off < 64; off <<= 1) {
    den += __shfl_xor(den, off);
#pragma unroll
    for (int j = 0; j < 8; ++j) acc[j] += __shfl_xor(acc[j], off);
  }
  if (slot == 0) {
    float inv = 1.f / den;
    float o[8];
#pragma unroll
    for (int j = 0; j < 8; ++j) {
      float v = acc[j] * inv + b1[chg * 8 + j];
      o[j] = v > 0.f ? v : (__expf(v) - 1.f);
    }
    float* dst = h1 + (size_t)wid * 64 + chg * 8;
#pragma unroll
    for (int j = 0; j < 8; ++j) dst[j] = o[j];
  }
}

// ---- GEMM2 + prep2 fused: xw2b(bf16) = h1 @ W2; ssrc2/sdst2 dots -----------
__global__ __launch_bounds__(256) void k_gemm2p(const float* __restrict__ h1,
                                                const float* __restrict__ W2,
                                                const float* __restrict__ asr,
                                                const float* __restrict__ adt,
                                                unsigned short* __restrict__ xw2b,
                                                float* __restrict__ ssrc,
                                                float* __restrict__ sdst, int Nn) {
  __shared__ float w[64 * 16];
  int tid = threadIdx.x;
  for (int i = tid; i < 1024; i += 256) w[i] = W2[i];
  __syncthreads();
  int idx = blockIdx.x * 256 + tid;
  if (idx >= Nn * 16) return;
  int n = idx >> 4, c = idx & 15;
  const float* hr = h1 + (size_t)n * 64;
  float acc = 0.f;
#pragma unroll 8
  for (int k = 0; k < 64; ++k) acc += hr[k] * w[k * 16 + c];
  xw2b[idx] = f2bf(acc);
  float ssv = acc * asr[c], sdv = acc * adt[c];
#pragma unroll
  for (int off = 1; off < 16; off <<= 1) {
    ssv += __shfl_xor(ssv, off);
    sdv += __shfl_xor(sdv, off);
  }
  if (c == 0) { ssrc[n] = ssv; sdst[n] = sdv; }
}

// ---------------- layer-2 aggregate (bf16 payload) + log_softmax ------------
__global__ __launch_bounds__(256) void k_agg2(const int* __restrict__ rowptr,
                                              const int* __restrict__ col,
                                              const float* __restrict__ ssrc,
                                              const float* __restrict__ sdst,
                                              const unsigned short* __restrict__ xw2b,
                                              const float* __restrict__ b2,
                                              float* __restrict__ out, int Nn) {
  int wid = (blockIdx.x * 256 + threadIdx.x) >> 6;
  if (wid >= Nn) return;
  int lane = threadIdx.x & 63;
  int slot = lane >> 4, c = lane & 15;
  float sd = sdst[wid];
  int start = rowptr[wid], end = rowptr[wid + 1];
  float den = 0.f, acc = 0.f;
  int i = start + slot;
  for (; i + 4 < end; i += 8) {
    int s0 = col[i], s1 = col[i + 4];
    float w0 = bf2f(xw2b[(size_t)s0 * 16 + c]);
    float w1 = bf2f(xw2b[(size_t)s1 * 16 + c]);
    float v0 = ssrc[s0] + sd; v0 = v0 > 0.f ? v0 : NEGS * v0;
    float v1 = ssrc[s1] + sd; v1 = v1 > 0.f ? v1 : NEGS * v1;
    float p0 = __expf(v0), p1 = __expf(v1);
    den += p0 + p1;
    acc = fmaf(p0, w0, acc);
    acc = fmaf(p1, w1, acc);
  }
  if (i < end) {
    int s = col[i];
    float v = ssrc[s] + sd;
    v = v > 0.f ? v : NEGS * v;
    float p = __expf(v);
    den += p;
    acc = fmaf(p, bf2f(xw2b[(size_t)s * 16 + c]), acc);
  }
  den += __shfl_xor(den, 16);
  den += __shfl_xor(den, 32);
  acc += __shfl_xor(acc, 16);
  acc += __shfl_xor(acc, 32);
  float o = acc / den + b2[c];
  float mx = o;
#pragma unroll
  for (int off = 1; off < 16; off <<= 1) mx = fmaxf(mx, __shfl_xor(mx, off));
  float ex = __expf(o - mx);
  float ssum = ex;
#pragma unroll
  for (int off = 1; off < 16; off <<= 1) ssum += __shfl_xor(ssum, off);
  float r = o - mx - __logf(ssum);
  if (slot == 0) out[(size_t)wid * 16 + c] = r;
}

extern "C" void kernel_launch(void* const* d_in, const int* in_sizes, int n_in,
                              void* d_out, int out_size, void* d_ws, size_t ws_size,
                              hipStream_t stream) {
  const float* x      = (const float*)d_in[0];
  const int* ei       = (const int*)d_in[1];
  const float* W1     = (const float*)d_in[2];
  const float* a_src1 = (const float*)d_in[3];
  const float* a_dst1 = (const float*)d_in[4];
  const float* b1     = (const float*)d_in[5];
  const float* W2     = (const float*)d_in[6];
  const float* a_src2 = (const float*)d_in[7];
  const float* a_dst2 = (const float*)d_in[8];
  const float* b2     = (const float*)d_in[9];

  const int F    = in_sizes[2] / 64;   // 500
  const int Nn   = in_sizes[0] / F;    // 100000
  const int E    = in_sizes[1] / 2;    // 1600000
  const int Etot = E + Nn;
  const int nck  = (F + 63) >> 6;
  const int Kp   = nck * 64;
  const int NB   = (Nn + (1 << BSH) - 1) >> BSH;   // 196 (<=256)
  const int NT   = (E + TS - 1) / TS;              // 391 (<=512)
  const int WCB  = (Kp * 64 + 255) / 256;          // wcvt blocks
  const int GB   = (Nn + 63) / 64;                 // gemm row-blocks
  const int G1   = (GB + 2) / 3;
  const int G2   = G1;
  const int G3   = GB - G1 - G2;

  // ---- workspace layout (4-byte units), no aliasing among concurrent users --
  float* ws = (float*)d_ws;
  unsigned short* xwb = (unsigned short*)ws;          // Nn*64 bf16
  float* h1     = ws + (size_t)Nn * 32;               // Nn*64
  float* ssrc1  = h1 + (size_t)Nn * 64;               // Nn*8
  float* sdst1  = ssrc1 + (size_t)Nn * 8;             // Nn*8
  int* rowptr   = (int*)(sdst1 + (size_t)Nn * 8);     // Nn+1
  int* col      = rowptr + Nn + 1;                    // Etot
  unsigned short* Wb = (unsigned short*)(col + ((Etot + 7) & ~7));  // Kp*64
  int* hist     = (int*)(Wb + (size_t)Kp * 64);       // NT*NB (fresh region)
  int* off_rel  = hist + (size_t)NT * NB;             // NT*NB
  int* total    = off_rel + (size_t)NT * NB;          // NB
  unsigned* pairs = (unsigned*)h1;                    // E (h1 unwritten until agg1)
  // layer-2 buffers alias xwb region (dead after k_agg1)
  unsigned short* xw2b = (unsigned short*)ws;         // Nn*16 bf16
  float* ssrc2  = ws + (size_t)Nn * 8;                // Nn
  float* sdst2  = ssrc2 + Nn;                         // Nn
  float* out2   = (float*)d_out;

  dim3 blk(256);

  // L1: wcvt || thist
  k_A<<<dim3(WCB + NT), blk, 0, stream>>>(W1, Wb, F, Kp, ei, hist, E, NB, WCB);
  // L2: bscan1 || gemm rows [0, G1)
  k_B1<<<dim3(NB + G1), blk, 0, stream>>>(hist, off_rel, total, NT, NB,
      x, Wb, xwb, a_src1, a_dst1, ssrc1, sdst1, Nn, F, nck, 0);
  // L3: pscatter || gemm rows [G1, G1+G2)
  k_B2<<<dim3(NT + G2), blk, 0, stream>>>(ei, off_rel, total, pairs, E, NB, NT,
      x, Wb, xwb, a_src1, a_dst1, ssrc1, sdst1, Nn, F, nck, G1);
  // L4: bcsr || gemm rows [G1+G2, GB)
  k_B3<<<dim3(NB + G3), blk, 0, stream>>>(pairs, total, rowptr, col, Nn, E, NB,
      x, Wb, xwb, a_src1, a_dst1, ssrc1, sdst1, Nn, F, nck, G1 + G2);
  // L5-L7: tail chain
  k_agg1<<<dim3((Nn * 64 + 255) / 256), blk, 0, stream>>>(
      rowptr, col, ssrc1, sdst1, xwb, b1, h1, Nn);
  k_gemm2p<<<dim3((Nn * 16 + 255) / 256), blk, 0, stream>>>(
      h1, W2, a_src2, a_dst2, xw2b, ssrc2, sdst2, Nn);
  k_agg2<<<dim3((Nn * 64 + 255) / 256), blk, 0, stream>>>(
      rowptr, col, ssrc2, sdst2, xw2b, b2, out2, Nn);
}

// Round 11
// 220.609 us; speedup vs baseline: 1.0852x; 1.0852x over previous
//
#include <hip/hip_runtime.h>
#include <hip/hip_bf16.h>
#include <math.h>

#define NEGS 0.2f
#define BSH 9                 // bucket shift: 512 nodes per bucket
#define TS 4096               // edges per partition tile

typedef __attribute__((ext_vector_type(8))) short bf16x8;
typedef __attribute__((ext_vector_type(8))) unsigned short u16x8;
typedef __attribute__((ext_vector_type(4))) float f32x4;

__device__ __forceinline__ unsigned short f2bf(float f) {
  __hip_bfloat16 h = __float2bfloat16(f);
  unsigned short u;
  __builtin_memcpy(&u, &h, 2);
  return u;
}
__device__ __forceinline__ float bf2f(unsigned short u) {
  return __uint_as_float((unsigned)u << 16);
}
__device__ __forceinline__ unsigned packbf(float lo, float hi) {
  return (unsigned)f2bf(lo) | ((unsigned)f2bf(hi) << 16);
}

// ---------------- device bodies (block-range fused) -------------------------

__device__ __forceinline__ void dev_wcvt(const float* __restrict__ W1,
                                         unsigned short* __restrict__ Wb,
                                         int K, int Kp, int blk) {
  int t = blk * 256 + threadIdx.x;
  if (t >= Kp * 64) return;
  int kg = t >> 6, c = t & 63;
  float f = (kg < K) ? W1[(size_t)kg * 64 + c] : 0.f;
  size_t off = ((size_t)((kg >> 5) * 4 + ((kg >> 3) & 3)) * 512) + c * 8 + (kg & 7);
  Wb[off] = f2bf(f);
}

__device__ __forceinline__ void dev_thist(const int* __restrict__ ei,
                                          int* __restrict__ hist,
                                          int E, int NB, int tile) {
  __shared__ int lh[256];
  const int t = threadIdx.x;
  lh[t] = 0;
  __syncthreads();
  const int e0 = tile * TS;
#pragma unroll
  for (int j = 0; j < TS / 256; ++j) {
    int e = e0 + j * 256 + t;
    if (e < E) atomicAdd(&lh[ei[E + e] >> BSH], 1);
  }
  __syncthreads();
  if (t < NB) hist[tile * NB + t] = lh[t];
}

__device__ __forceinline__ void dev_bscan1(const int* __restrict__ hist,
                                           int* __restrict__ off_rel,
                                           int* __restrict__ total,
                                           int NT, int NB, int b) {
  __shared__ int sh[256];
  const int t = threadIdx.x;
  int t0 = 2 * t, t1 = 2 * t + 1;
  int v0 = (t0 < NT) ? hist[t0 * NB + b] : 0;
  int v1 = (t1 < NT) ? hist[t1 * NB + b] : 0;
  int ps = v0 + v1;
  sh[t] = ps;
  __syncthreads();
  for (int off = 1; off < 256; off <<= 1) {
    int v = (t >= off) ? sh[t - off] : 0;
    __syncthreads();
    sh[t] += v;
    __syncthreads();
  }
  int excl = sh[t] - ps;
  if (t0 < NT) off_rel[t0 * NB + b] = excl;
  if (t1 < NT) off_rel[t1 * NB + b] = excl + v0;
  if (t == 255) total[b] = sh[255];
}

__device__ __forceinline__ void dev_pscatter(const int* __restrict__ ei,
                                             const int* __restrict__ off_rel,
                                             const int* __restrict__ total,
                                             unsigned* __restrict__ pairs,
                                             int E, int NB, int tile) {
  __shared__ int cur[256];
  __shared__ int sb[256];
  const int t = threadIdx.x;
  int v = (t < NB) ? total[t] : 0;
  sb[t] = v;
  __syncthreads();
  for (int off = 1; off < 256; off <<= 1) {
    int x = (t >= off) ? sb[t - off] : 0;
    __syncthreads();
    sb[t] += x;
    __syncthreads();
  }
  if (t < NB) cur[t] = (sb[t] - v) + off_rel[tile * NB + t];
  __syncthreads();
  const int e0 = tile * TS;
#pragma unroll
  for (int j = 0; j < TS / 256; ++j) {
    int e = e0 + j * 256 + t;
    if (e < E) {
      int s = ei[e], d = ei[E + e];
      int pos = atomicAdd(&cur[d >> BSH], 1);
      pairs[pos] = ((unsigned)(d & ((1 << BSH) - 1)) << 23) | (unsigned)s;
    }
  }
}

__device__ __forceinline__ void dev_bcsr(const unsigned* __restrict__ pairs,
                                         const int* __restrict__ total,
                                         int* __restrict__ rowptr,
                                         int* __restrict__ col,
                                         int Nn, int E, int NB, int b) {
  __shared__ int cnt[1 << BSH];
  __shared__ int cu[1 << BSH];
  __shared__ int sh[256];
  __shared__ int P0, P1;
  const int t = threadIdx.x;
  const int d0 = b << BSH;
  const int dn = min(1 << BSH, Nn - d0);
  {
    int v = (t < NB) ? total[t] : 0;
    sh[t] = v;
    __syncthreads();
    for (int off = 1; off < 256; off <<= 1) {
      int x = (t >= off) ? sh[t - off] : 0;
      __syncthreads();
      sh[t] += x;
      __syncthreads();
    }
    if (t == b) { P0 = sh[t] - v; P1 = sh[t]; }
    __syncthreads();
  }
  const int p0 = P0, p1 = P1;
  const int rpb = p0 + d0;
  cnt[2 * t] = (2 * t < dn) ? 1 : 0;
  cnt[2 * t + 1] = (2 * t + 1 < dn) ? 1 : 0;
  __syncthreads();
  for (int i = p0 + t; i < p1; i += 256) atomicAdd(&cnt[pairs[i] >> 23], 1);
  __syncthreads();
  int a0 = cnt[2 * t], a1 = cnt[2 * t + 1];
  int ps = a0 + a1;
  sh[t] = ps;
  __syncthreads();
  for (int off = 1; off < 256; off <<= 1) {
    int v = (t >= off) ? sh[t - off] : 0;
    __syncthreads();
    sh[t] += v;
    __syncthreads();
  }
  int excl = sh[t] - ps;
#pragma unroll
  for (int u = 0; u < 2; ++u) {
    int i = 2 * t + u;
    int ex = (u == 0) ? excl : excl + a0;
    if (i < dn) {
      rowptr[d0 + i] = rpb + ex;
      col[rpb + ex] = d0 + i;   // self-loop
      cu[i] = ex + 1;
    }
  }
  if (b == NB - 1 && t == 0) rowptr[Nn] = E + Nn;
  __syncthreads();
  for (int i = p0 + t; i < p1; i += 256) {
    unsigned p = pairs[i];
    int pos = atomicAdd(&cu[p >> 23], 1);
    col[rpb + pos] = (int)(p & 0x7fffffu);
  }
}

// GEMM1 slice (no LDS, reg-dbuf A prefetch) + fused sdst epilogue
__device__ __forceinline__ void dev_gemm(const float* __restrict__ A,
                                         const unsigned short* __restrict__ Wb,
                                         unsigned short* __restrict__ C,
                                         const float* __restrict__ a1d,
                                         float* __restrict__ sdst,
                                         int M, int K, int nck, int rowblk) {
  const int tid = threadIdx.x;
  const int lane = tid & 63;
  const int w = tid >> 6;
  const int r15 = lane & 15;
  const int kgrp = lane >> 4;
  const int bm = rowblk * 64;
  const int row = bm + w * 16 + r15;
  const float* Ar = A + (size_t)(row < M ? row : (M - 1)) * K;
  const int NIT = 2 * nck;
  const int ITV = (K >= 40) ? ((K - 40) / 32 + 1) : 0;   // vector-safe iters

  f32x4 acc[4] = {};

  float4 c0, c1;
  {
    // it = 0 is always vector-safe for K >= 40
    const float4* g = (const float4*)(Ar + kgrp * 8);
    c0 = g[0]; c1 = g[1];
  }
  for (int it = 0; it < NIT; ++it) {
    float4 n0, n1;
    if (it + 1 < NIT) {
      int k0 = (it + 1) * 32 + kgrp * 8;
      if (it + 1 < ITV) {
        const float4* g = (const float4*)(Ar + k0);
        n0 = g[0]; n1 = g[1];
      } else {
        float tmp[8];
#pragma unroll
        for (int j = 0; j < 8; ++j) {
          int kk = k0 + j;
          tmp[j] = (kk < K) ? Ar[kk] : 0.f;
        }
        n0 = make_float4(tmp[0], tmp[1], tmp[2], tmp[3]);
        n1 = make_float4(tmp[4], tmp[5], tmp[6], tmp[7]);
      }
    }
    const unsigned short* bb = Wb + ((size_t)(it * 4 + kgrp) * 512) + r15 * 8;
    bf16x8 bf4[4];
#pragma unroll
    for (int nc = 0; nc < 4; ++nc)
      bf4[nc] = *(const bf16x8*)(bb + nc * 128);
    unsigned pk[4] = { packbf(c0.x, c0.y), packbf(c0.z, c0.w),
                       packbf(c1.x, c1.y), packbf(c1.z, c1.w) };
    bf16x8 af = *(bf16x8*)pk;
#pragma unroll
    for (int nc = 0; nc < 4; ++nc)
      acc[nc] = __builtin_amdgcn_mfma_f32_16x16x32_bf16(af, bf4[nc], acc[nc], 0, 0, 0);
    c0 = n0; c1 = n1;
  }
  // epilogue: bf16 C write + fused sdst dot (a_dst half only)
  float dv[4];
#pragma unroll
  for (int nc = 0; nc < 4; ++nc) dv[nc] = a1d[nc * 16 + r15];
#pragma unroll
  for (int j = 0; j < 4; ++j) {
    int grow = bm + w * 16 + kgrp * 4 + j;
    bool liv = grow < M;
#pragma unroll
    for (int nc = 0; nc < 4; ++nc) {
      if (liv) C[(size_t)grow * 64 + nc * 16 + r15] = f2bf(acc[nc][j]);
      float sd = acc[nc][j] * dv[nc];
      sd += __shfl_xor(sd, 1); sd += __shfl_xor(sd, 2); sd += __shfl_xor(sd, 4);
      if ((r15 & 7) == 0 && liv)
        sdst[grow * 8 + nc * 2 + (r15 >> 3)] = sd;
    }
  }
}

// ---------------- fused launch wrappers -------------------------------------
__global__ __launch_bounds__(256) void k_A(const float* __restrict__ W1,
                                           unsigned short* __restrict__ Wb,
                                           int K, int Kp,
                                           const int* __restrict__ ei,
                                           int* __restrict__ hist,
                                           int E, int NB, int WCB) {
  int b = blockIdx.x;
  if (b < WCB) dev_wcvt(W1, Wb, K, Kp, b);
  else dev_thist(ei, hist, E, NB, b - WCB);
}

__global__ __launch_bounds__(256) void k_B1(const int* __restrict__ hist,
                                            int* __restrict__ off_rel,
                                            int* __restrict__ total,
                                            int NT, int NB,
                                            const float* __restrict__ A,
                                            const unsigned short* __restrict__ Wb,
                                            unsigned short* __restrict__ C,
                                            const float* __restrict__ a1d,
                                            float* __restrict__ sdst,
                                            int M, int K, int nck, int R0) {
  int b = blockIdx.x;
  if (b < NB) dev_bscan1(hist, off_rel, total, NT, NB, b);
  else dev_gemm(A, Wb, C, a1d, sdst, M, K, nck, b - NB + R0);
}

__global__ __launch_bounds__(256) void k_B2(const int* __restrict__ ei,
                                            const int* __restrict__ off_rel,
                                            const int* __restrict__ total,
                                            unsigned* __restrict__ pairs,
                                            int E, int NB, int NT,
                                            const float* __restrict__ A,
                                            const unsigned short* __restrict__ Wb,
                                            unsigned short* __restrict__ C,
                                            const float* __restrict__ a1d,
                                            float* __restrict__ sdst,
                                            int M, int K, int nck, int R0) {
  int b = blockIdx.x;
  if (b < NT) dev_pscatter(ei, off_rel, total, pairs, E, NB, b);
  else dev_gemm(A, Wb, C, a1d, sdst, M, K, nck, b - NT + R0);
}

__global__ __launch_bounds__(256) void k_B3(const unsigned* __restrict__ pairs,
                                            const int* __restrict__ total,
                                            int* __restrict__ rowptr,
                                            int* __restrict__ col,
                                            int Nn, int E, int NB,
                                            const float* __restrict__ A,
                                            const unsigned short* __restrict__ Wb,
                                            unsigned short* __restrict__ C,
                                            const float* __restrict__ a1d,
                                            float* __restrict__ sdst,
                                            int M, int K, int nck, int R0) {
  int b = blockIdx.x;
  if (b < NB) dev_bcsr(pairs, total, rowptr, col, Nn, E, NB, b);
  else dev_gemm(A, Wb, C, a1d, sdst, M, K, nck, b - NB + R0);
}

// ------- layer-1 aggregate: 8 edges/iter; ssrc computed IN-REGISTER ---------
__global__ __launch_bounds__(256) void k_agg1(const int* __restrict__ rowptr,
                                              const int* __restrict__ col,
                                              const float* __restrict__ a1s,
                                              const float* __restrict__ sdst,
                                              const unsigned short* __restrict__ xwb,
                                              const float* __restrict__ b1,
                                              float* __restrict__ h1, int Nn) {
  int wid = (blockIdx.x * 256 + threadIdx.x) >> 6;
  if (wid >= Nn) return;
  int lane = threadIdx.x & 63;
  int slot = lane >> 3;     // edge slot 0..7
  int chg = lane & 7;       // head 0..7
  float asr[8];
#pragma unroll
  for (int j = 0; j < 8; ++j) asr[j] = a1s[chg * 8 + j];
  float sd = sdst[wid * 8 + chg];
  int start = rowptr[wid], end = rowptr[wid + 1];
  float den = 0.f;
  float acc[8] = {};
  for (int it = start; it < end; it += 8) {
    int idx = it + slot;
    bool ok = idx < end;
    int s = col[ok ? idx : start];
    u16x8 pv = *(const u16x8*)(xwb + (size_t)s * 64 + chg * 8);  // head chg row
    float f[8];
#pragma unroll
    for (int j = 0; j < 8; ++j) f[j] = bf2f(pv[j]);
    float ss = 0.f;
#pragma unroll
    for (int j = 0; j < 8; ++j) ss = fmaf(f[j], asr[j], ss);   // ssrc in-register
    float v = ss + sd;
    v = v > 0.f ? v : NEGS * v;
    float p = ok ? __expf(v) : 0.f;
    den += p;
#pragma unroll
    for (int j = 0; j < 8; ++j) acc[j] = fmaf(p, f[j], acc[j]);
  }
#pragma unroll
  for (int off = 8; off < 64; off <<= 1) {
    den += __shfl_xor(den, off);
#pragma unroll
    for (int j = 0; j < 8; ++j) acc[j] += __shfl_xor(acc[j], off);
  }
  if (slot == 0) {
    float inv = 1.f / den;
    float o[8];
#pragma unroll
    for (int j = 0; j < 8; ++j) {
      float v = acc[j] * inv + b1[chg * 8 + j];
      o[j] = v > 0.f ? v : (__expf(v) - 1.f);
    }
    float* dst = h1 + (size_t)wid * 64 + chg * 8;
#pragma unroll
    for (int j = 0; j < 8; ++j) dst[j] = o[j];
  }
}

// ---- GEMM2 + prep2 fused: xw2b(bf16) = h1 @ W2; ssrc2/sdst2 dots -----------
__global__ __launch_bounds__(256) void k_gemm2p(const float* __restrict__ h1,
                                                const float* __restrict__ W2,
                                                const float* __restrict__ asr,
                                                const float* __restrict__ adt,
                                                unsigned short* __restrict__ xw2b,
                                                float* __restrict__ ssrc,
                                                float* __restrict__ sdst, int Nn) {
  __shared__ float w[64 * 16];
  int tid = threadIdx.x;
  for (int i = tid; i < 1024; i += 256) w[i] = W2[i];
  __syncthreads();
  int idx = blockIdx.x * 256 + tid;
  if (idx >= Nn * 16) return;
  int n = idx >> 4, c = idx & 15;
  const float* hr = h1 + (size_t)n * 64;
  float acc = 0.f;
#pragma unroll 8
  for (int k = 0; k < 64; ++k) acc += hr[k] * w[k * 16 + c];
  xw2b[idx] = f2bf(acc);
  float ssv = acc * asr[c], sdv = acc * adt[c];
#pragma unroll
  for (int off = 1; off < 16; off <<= 1) {
    ssv += __shfl_xor(ssv, off);
    sdv += __shfl_xor(sdv, off);
  }
  if (c == 0) { ssrc[n] = ssv; sdst[n] = sdv; }
}

// ---------------- layer-2 aggregate (bf16 payload) + log_softmax ------------
__global__ __launch_bounds__(256) void k_agg2(const int* __restrict__ rowptr,
                                              const int* __restrict__ col,
                                              const float* __restrict__ ssrc,
                                              const float* __restrict__ sdst,
                                              const unsigned short* __restrict__ xw2b,
                                              const float* __restrict__ b2,
                                              float* __restrict__ out, int Nn) {
  int wid = (blockIdx.x * 256 + threadIdx.x) >> 6;
  if (wid >= Nn) return;
  int lane = threadIdx.x & 63;
  int slot = lane >> 4, c = lane & 15;
  float sd = sdst[wid];
  int start = rowptr[wid], end = rowptr[wid + 1];
  float den = 0.f, acc = 0.f;
  int i = start + slot;
  for (; i + 4 < end; i += 8) {
    int s0 = col[i], s1 = col[i + 4];
    float w0 = bf2f(xw2b[(size_t)s0 * 16 + c]);
    float w1 = bf2f(xw2b[(size_t)s1 * 16 + c]);
    float v0 = ssrc[s0] + sd; v0 = v0 > 0.f ? v0 : NEGS * v0;
    float v1 = ssrc[s1] + sd; v1 = v1 > 0.f ? v1 : NEGS * v1;
    float p0 = __expf(v0), p1 = __expf(v1);
    den += p0 + p1;
    acc = fmaf(p0, w0, acc);
    acc = fmaf(p1, w1, acc);
  }
  if (i < end) {
    int s = col[i];
    float v = ssrc[s] + sd;
    v = v > 0.f ? v : NEGS * v;
    float p = __expf(v);
    den += p;
    acc = fmaf(p, bf2f(xw2b[(size_t)s * 16 + c]), acc);
  }
  den += __shfl_xor(den, 16);
  den += __shfl_xor(den, 32);
  acc += __shfl_xor(acc, 16);
  acc += __shfl_xor(acc, 32);
  float o = acc / den + b2[c];
  float mx = o;
#pragma unroll
  for (int off = 1; off < 16; off <<= 1) mx = fmaxf(mx, __shfl_xor(mx, off));
  float ex = __expf(o - mx);
  float ssum = ex;
#pragma unroll
  for (int off = 1; off < 16; off <<= 1) ssum += __shfl_xor(ssum, off);
  float r = o - mx - __logf(ssum);
  if (slot == 0) out[(size_t)wid * 16 + c] = r;
}

extern "C" void kernel_launch(void* const* d_in, const int* in_sizes, int n_in,
                              void* d_out, int out_size, void* d_ws, size_t ws_size,
                              hipStream_t stream) {
  const float* x      = (const float*)d_in[0];
  const int* ei       = (const int*)d_in[1];
  const float* W1     = (const float*)d_in[2];
  const float* a_src1 = (const float*)d_in[3];
  const float* a_dst1 = (const float*)d_in[4];
  const float* b1     = (const float*)d_in[5];
  const float* W2     = (const float*)d_in[6];
  const float* a_src2 = (const float*)d_in[7];
  const float* a_dst2 = (const float*)d_in[8];
  const float* b2     = (const float*)d_in[9];

  const int F    = in_sizes[2] / 64;   // 500
  const int Nn   = in_sizes[0] / F;    // 100000
  const int E    = in_sizes[1] / 2;    // 1600000
  const int Etot = E + Nn;
  const int nck  = (F + 63) >> 6;
  const int Kp   = nck * 64;
  const int NB   = (Nn + (1 << BSH) - 1) >> BSH;   // 196 (<=256)
  const int NT   = (E + TS - 1) / TS;              // 391 (<=512)
  const int WCB  = (Kp * 64 + 255) / 256;
  const int GB   = (Nn + 63) / 64;
  const int G1   = (GB + 2) / 3;
  const int G2   = G1;
  const int G3   = GB - G1 - G2;

  // ---- workspace layout (4-byte units) ----
  float* ws = (float*)d_ws;
  unsigned short* xwb = (unsigned short*)ws;          // Nn*64 bf16
  float* h1     = ws + (size_t)Nn * 32;               // Nn*64
  float* ssrc1  = h1 + (size_t)Nn * 64;               // Nn*8 (unused now)
  float* sdst1  = ssrc1 + (size_t)Nn * 8;             // Nn*8
  int* rowptr   = (int*)(sdst1 + (size_t)Nn * 8);     // Nn+1
  int* col      = rowptr + Nn + 1;                    // Etot
  unsigned short* Wb = (unsigned short*)(col + ((Etot + 7) & ~7));  // Kp*64
  int* hist     = (int*)(Wb + (size_t)Kp * 64);       // NT*NB
  int* off_rel  = hist + (size_t)NT * NB;             // NT*NB
  int* total    = off_rel + (size_t)NT * NB;          // NB
  unsigned* pairs = (unsigned*)h1;                    // E (h1 unwritten until agg1)
  // layer-2 buffers alias xwb region (dead after k_agg1)
  unsigned short* xw2b = (unsigned short*)ws;         // Nn*16 bf16
  float* ssrc2  = ws + (size_t)Nn * 8;                // Nn
  float* sdst2  = ssrc2 + Nn;                         // Nn
  float* out2   = (float*)d_out;

  dim3 blk(256);

  // L1: wcvt || thist
  k_A<<<dim3(WCB + NT), blk, 0, stream>>>(W1, Wb, F, Kp, ei, hist, E, NB, WCB);
  // L2: bscan1 || gemm rows [0, G1)
  k_B1<<<dim3(NB + G1), blk, 0, stream>>>(hist, off_rel, total, NT, NB,
      x, Wb, xwb, a_dst1, sdst1, Nn, F, nck, 0);
  // L3: pscatter || gemm rows [G1, G1+G2)
  k_B2<<<dim3(NT + G2), blk, 0, stream>>>(ei, off_rel, total, pairs, E, NB, NT,
      x, Wb, xwb, a_dst1, sdst1, Nn, F, nck, G1);
  // L4: bcsr || gemm rows [G1+G2, GB)
  k_B3<<<dim3(NB + G3), blk, 0, stream>>>(pairs, total, rowptr, col, Nn, E, NB,
      x, Wb, xwb, a_dst1, sdst1, Nn, F, nck, G1 + G2);
  // L5-L7: tail chain
  k_agg1<<<dim3((Nn * 64 + 255) / 256), blk, 0, stream>>>(
      rowptr, col, a_src1, sdst1, xwb, b1, h1, Nn);
  k_gemm2p<<<dim3((Nn * 16 + 255) / 256), blk, 0, stream>>>(
      h1, W2, a_src2, a_dst2, xw2b, ssrc2, sdst2, Nn);
  k_agg2<<<dim3((Nn * 64 + 255) / 256), blk, 0, stream>>>(
      rowptr, col, ssrc2, sdst2, xw2b, b2, out2, Nn);
}

// Round 12
// 206.330 us; speedup vs baseline: 1.1603x; 1.0692x over previous
//
#include <hip/hip_runtime.h>
#include <hip/hip_bf16.h>
#include <math.h>

#define NEGS 0.2f
#define BSH 9                 // bucket shift: 512 nodes per bucket
#define TS 4096               // edges per partition tile

typedef __attribute__((ext_vector_type(8))) short bf16x8;
typedef __attribute__((ext_vector_type(8))) unsigned short u16x8;
typedef __attribute__((ext_vector_type(4))) float f32x4;

__device__ __forceinline__ unsigned short f2bf(float f) {
  __hip_bfloat16 h = __float2bfloat16(f);
  unsigned short u;
  __builtin_memcpy(&u, &h, 2);
  return u;
}
__device__ __forceinline__ float bf2f(unsigned short u) {
  return __uint_as_float((unsigned)u << 16);
}
__device__ __forceinline__ unsigned packbf(float lo, float hi) {
  return (unsigned)f2bf(lo) | ((unsigned)f2bf(hi) << 16);
}

// ---------------- device bodies (block-range fused) -------------------------

__device__ __forceinline__ void dev_wcvt(const float* __restrict__ W1,
                                         unsigned short* __restrict__ Wb,
                                         int K, int Kp, int blk) {
  int t = blk * 256 + threadIdx.x;
  if (t >= Kp * 64) return;
  int kg = t >> 6, c = t & 63;
  float f = (kg < K) ? W1[(size_t)kg * 64 + c] : 0.f;
  size_t off = ((size_t)((kg >> 5) * 4 + ((kg >> 3) & 3)) * 512) + c * 8 + (kg & 7);
  Wb[off] = f2bf(f);
}

// W2 -> lane-packed W2p[lane*16 + j*2 + c'] = W2[(chg*8+j)*16 + slot*2 + c']
__device__ __forceinline__ void dev_w2p(const float* __restrict__ W2,
                                        float* __restrict__ W2p) {
  int t = threadIdx.x;
#pragma unroll
  for (int u = 0; u < 4; ++u) {
    int i = u * 256 + t;        // 0..1023
    int lane = i >> 4, r = i & 15;
    int slot = lane >> 3, chg = lane & 7;
    int j = r >> 1, cp = r & 1;
    W2p[i] = W2[(chg * 8 + j) * 16 + slot * 2 + cp];
  }
}

__device__ __forceinline__ void dev_thist(const int* __restrict__ ei,
                                          int* __restrict__ hist,
                                          int E, int NB, int tile) {
  __shared__ int lh[256];
  const int t = threadIdx.x;
  lh[t] = 0;
  __syncthreads();
  const int e0 = tile * TS;
#pragma unroll
  for (int j = 0; j < TS / 256; ++j) {
    int e = e0 + j * 256 + t;
    if (e < E) atomicAdd(&lh[ei[E + e] >> BSH], 1);
  }
  __syncthreads();
  if (t < NB) hist[tile * NB + t] = lh[t];
}

__device__ __forceinline__ void dev_bscan1(const int* __restrict__ hist,
                                           int* __restrict__ off_rel,
                                           int* __restrict__ total,
                                           int NT, int NB, int b) {
  __shared__ int sh[256];
  const int t = threadIdx.x;
  int t0 = 2 * t, t1 = 2 * t + 1;
  int v0 = (t0 < NT) ? hist[t0 * NB + b] : 0;
  int v1 = (t1 < NT) ? hist[t1 * NB + b] : 0;
  int ps = v0 + v1;
  sh[t] = ps;
  __syncthreads();
  for (int off = 1; off < 256; off <<= 1) {
    int v = (t >= off) ? sh[t - off] : 0;
    __syncthreads();
    sh[t] += v;
    __syncthreads();
  }
  int excl = sh[t] - ps;
  if (t0 < NT) off_rel[t0 * NB + b] = excl;
  if (t1 < NT) off_rel[t1 * NB + b] = excl + v0;
  if (t == 255) total[b] = sh[255];
}

__device__ __forceinline__ void dev_pscatter(const int* __restrict__ ei,
                                             const int* __restrict__ off_rel,
                                             const int* __restrict__ total,
                                             unsigned* __restrict__ pairs,
                                             int E, int NB, int tile) {
  __shared__ int cur[256];
  __shared__ int sb[256];
  const int t = threadIdx.x;
  int v = (t < NB) ? total[t] : 0;
  sb[t] = v;
  __syncthreads();
  for (int off = 1; off < 256; off <<= 1) {
    int x = (t >= off) ? sb[t - off] : 0;
    __syncthreads();
    sb[t] += x;
    __syncthreads();
  }
  if (t < NB) cur[t] = (sb[t] - v) + off_rel[tile * NB + t];
  __syncthreads();
  const int e0 = tile * TS;
#pragma unroll
  for (int j = 0; j < TS / 256; ++j) {
    int e = e0 + j * 256 + t;
    if (e < E) {
      int s = ei[e], d = ei[E + e];
      int pos = atomicAdd(&cur[d >> BSH], 1);
      pairs[pos] = ((unsigned)(d & ((1 << BSH) - 1)) << 23) | (unsigned)s;
    }
  }
}

__device__ __forceinline__ void dev_bcsr(const unsigned* __restrict__ pairs,
                                         const int* __restrict__ total,
                                         int* __restrict__ rowptr,
                                         int* __restrict__ col,
                                         int Nn, int E, int NB, int b) {
  __shared__ int cnt[1 << BSH];
  __shared__ int cu[1 << BSH];
  __shared__ int sh[256];
  __shared__ int P0, P1;
  const int t = threadIdx.x;
  const int d0 = b << BSH;
  const int dn = min(1 << BSH, Nn - d0);
  {
    int v = (t < NB) ? total[t] : 0;
    sh[t] = v;
    __syncthreads();
    for (int off = 1; off < 256; off <<= 1) {
      int x = (t >= off) ? sh[t - off] : 0;
      __syncthreads();
      sh[t] += x;
      __syncthreads();
    }
    if (t == b) { P0 = sh[t] - v; P1 = sh[t]; }
    __syncthreads();
  }
  const int p0 = P0, p1 = P1;
  const int rpb = p0 + d0;
  cnt[2 * t] = (2 * t < dn) ? 1 : 0;
  cnt[2 * t + 1] = (2 * t + 1 < dn) ? 1 : 0;
  __syncthreads();
  for (int i = p0 + t; i < p1; i += 256) atomicAdd(&cnt[pairs[i] >> 23], 1);
  __syncthreads();
  int a0 = cnt[2 * t], a1 = cnt[2 * t + 1];
  int ps = a0 + a1;
  sh[t] = ps;
  __syncthreads();
  for (int off = 1; off < 256; off <<= 1) {
    int v = (t >= off) ? sh[t - off] : 0;
    __syncthreads();
    sh[t] += v;
    __syncthreads();
  }
  int excl = sh[t] - ps;
#pragma unroll
  for (int u = 0; u < 2; ++u) {
    int i = 2 * t + u;
    int ex = (u == 0) ? excl : excl + a0;
    if (i < dn) {
      rowptr[d0 + i] = rpb + ex;
      col[rpb + ex] = d0 + i;   // self-loop
      cu[i] = ex + 1;
    }
  }
  if (b == NB - 1 && t == 0) rowptr[Nn] = E + Nn;
  __syncthreads();
  for (int i = p0 + t; i < p1; i += 256) {
    unsigned p = pairs[i];
    int pos = atomicAdd(&cu[p >> 23], 1);
    col[rpb + pos] = (int)(p & 0x7fffffu);
  }
}

// GEMM1 slice (no LDS, depth-2 A prefetch) + fused sdst epilogue
__device__ __forceinline__ void dev_gemm(const float* __restrict__ A,
                                         const unsigned short* __restrict__ Wb,
                                         unsigned short* __restrict__ C,
                                         const float* __restrict__ a1d,
                                         float* __restrict__ sdst,
                                         int M, int K, int nck, int rowblk) {
  const int tid = threadIdx.x;
  const int lane = tid & 63;
  const int w = tid >> 6;
  const int r15 = lane & 15;
  const int kgrp = lane >> 4;
  const int bm = rowblk * 64;
  const int row = bm + w * 16 + r15;
  const float* Ar = A + (size_t)(row < M ? row : (M - 1)) * K;
  const int NIT = 2 * nck;
  const int ITV = (K >= 40) ? ((K - 40) / 32 + 1) : 0;   // vector-safe iters

  f32x4 acc[4] = {};

  auto loadA = [&](int it, float4& o0, float4& o1) {
    int k0 = it * 32 + kgrp * 8;
    if (it < ITV) {
      const float4* g = (const float4*)(Ar + k0);
      o0 = g[0]; o1 = g[1];
    } else {
      float tmp[8];
#pragma unroll
      for (int j = 0; j < 8; ++j) {
        int kk = k0 + j;
        tmp[j] = (kk < K) ? Ar[kk] : 0.f;
      }
      o0 = make_float4(tmp[0], tmp[1], tmp[2], tmp[3]);
      o1 = make_float4(tmp[4], tmp[5], tmp[6], tmp[7]);
    }
  };

  float4 c0, c1, d0, d1;
  loadA(0, c0, c1);
  if (NIT > 1) loadA(1, d0, d1);
  for (int it = 0; it < NIT; ++it) {
    float4 e0, e1;
    if (it + 2 < NIT) loadA(it + 2, e0, e1);
    const unsigned short* bb = Wb + ((size_t)(it * 4 + kgrp) * 512) + r15 * 8;
    bf16x8 bf4[4];
#pragma unroll
    for (int nc = 0; nc < 4; ++nc)
      bf4[nc] = *(const bf16x8*)(bb + nc * 128);
    unsigned pk[4] = { packbf(c0.x, c0.y), packbf(c0.z, c0.w),
                       packbf(c1.x, c1.y), packbf(c1.z, c1.w) };
    bf16x8 af = *(bf16x8*)pk;
#pragma unroll
    for (int nc = 0; nc < 4; ++nc)
      acc[nc] = __builtin_amdgcn_mfma_f32_16x16x32_bf16(af, bf4[nc], acc[nc], 0, 0, 0);
    c0 = d0; c1 = d1;
    d0 = e0; d1 = e1;
  }
  // epilogue: bf16 C write + fused sdst dot (a_dst half only)
  float dv[4];
#pragma unroll
  for (int nc = 0; nc < 4; ++nc) dv[nc] = a1d[nc * 16 + r15];
#pragma unroll
  for (int j = 0; j < 4; ++j) {
    int grow = bm + w * 16 + kgrp * 4 + j;
    bool liv = grow < M;
#pragma unroll
    for (int nc = 0; nc < 4; ++nc) {
      if (liv) C[(size_t)grow * 64 + nc * 16 + r15] = f2bf(acc[nc][j]);
      float sd = acc[nc][j] * dv[nc];
      sd += __shfl_xor(sd, 1); sd += __shfl_xor(sd, 2); sd += __shfl_xor(sd, 4);
      if ((r15 & 7) == 0 && liv)
        sdst[grow * 8 + nc * 2 + (r15 >> 3)] = sd;
    }
  }
}

// ---------------- fused launch wrappers -------------------------------------
__global__ __launch_bounds__(256) void k_A(const float* __restrict__ W1,
                                           unsigned short* __restrict__ Wb,
                                           int K, int Kp,
                                           const int* __restrict__ ei,
                                           int* __restrict__ hist,
                                           int E, int NB, int WCB,
                                           const float* __restrict__ W2,
                                           float* __restrict__ W2p) {
  int b = blockIdx.x;
  if (b < WCB) dev_wcvt(W1, Wb, K, Kp, b);
  else if (b == WCB) dev_w2p(W2, W2p);
  else dev_thist(ei, hist, E, NB, b - WCB - 1);
}

__global__ __launch_bounds__(256) void k_B1(const int* __restrict__ hist,
                                            int* __restrict__ off_rel,
                                            int* __restrict__ total,
                                            int NT, int NB,
                                            const float* __restrict__ A,
                                            const unsigned short* __restrict__ Wb,
                                            unsigned short* __restrict__ C,
                                            const float* __restrict__ a1d,
                                            float* __restrict__ sdst,
                                            int M, int K, int nck, int R0) {
  int b = blockIdx.x;
  if (b < NB) dev_bscan1(hist, off_rel, total, NT, NB, b);
  else dev_gemm(A, Wb, C, a1d, sdst, M, K, nck, b - NB + R0);
}

__global__ __launch_bounds__(256) void k_B2(const int* __restrict__ ei,
                                            const int* __restrict__ off_rel,
                                            const int* __restrict__ total,
                                            unsigned* __restrict__ pairs,
                                            int E, int NB, int NT,
                                            const float* __restrict__ A,
                                            const unsigned short* __restrict__ Wb,
                                            unsigned short* __restrict__ C,
                                            const float* __restrict__ a1d,
                                            float* __restrict__ sdst,
                                            int M, int K, int nck, int R0) {
  int b = blockIdx.x;
  if (b < NT) dev_pscatter(ei, off_rel, total, pairs, E, NB, b);
  else dev_gemm(A, Wb, C, a1d, sdst, M, K, nck, b - NT + R0);
}

__global__ __launch_bounds__(256) void k_B3(const unsigned* __restrict__ pairs,
                                            const int* __restrict__ total,
                                            int* __restrict__ rowptr,
                                            int* __restrict__ col,
                                            int Nn, int E, int NB,
                                            const float* __restrict__ A,
                                            const unsigned short* __restrict__ Wb,
                                            unsigned short* __restrict__ C,
                                            const float* __restrict__ a1d,
                                            float* __restrict__ sdst,
                                            int M, int K, int nck, int R0) {
  int b = blockIdx.x;
  if (b < NB) dev_bcsr(pairs, total, rowptr, col, Nn, E, NB, b);
  else dev_gemm(A, Wb, C, a1d, sdst, M, K, nck, b - NB + R0);
}

// ------- layer-1 aggregate + FUSED gemm2/prep2: one wave per node -----------
// edge loop: lane = slot(8) x head(8), ssrc in-register;
// epilogue: bias+ELU in-register, xw2 = h1@W2 via lane-packed W2p, attn dots.
__global__ __launch_bounds__(256) void k_agg1f(const int* __restrict__ rowptr,
                                               const int* __restrict__ col,
                                               const float* __restrict__ a1s,
                                               const float* __restrict__ sdst,
                                               const unsigned short* __restrict__ xwb,
                                               const float* __restrict__ b1,
                                               const float* __restrict__ W2p,
                                               const float* __restrict__ a2s,
                                               const float* __restrict__ a2d,
                                               unsigned short* __restrict__ xw2b,
                                               float* __restrict__ ssrc2,
                                               float* __restrict__ sdst2, int Nn) {
  int wid = (blockIdx.x * 256 + threadIdx.x) >> 6;
  if (wid >= Nn) return;
  int lane = threadIdx.x & 63;
  int slot = lane >> 3;     // edge slot 0..7 / output ch pair
  int chg = lane & 7;       // head 0..7
  float asr[8];
#pragma unroll
  for (int j = 0; j < 8; ++j) asr[j] = a1s[chg * 8 + j];
  float sd = sdst[wid * 8 + chg];
  int start = rowptr[wid], end = rowptr[wid + 1];
  float den = 0.f;
  float acc[8] = {};
  for (int it = start; it < end; it += 8) {
    int idx = it + slot;
    bool ok = idx < end;
    int s = col[ok ? idx : start];
    u16x8 pv = *(const u16x8*)(xwb + (size_t)s * 64 + chg * 8);
    float f[8];
#pragma unroll
    for (int j = 0; j < 8; ++j) f[j] = bf2f(pv[j]);
    float ss = 0.f;
#pragma unroll
    for (int j = 0; j < 8; ++j) ss = fmaf(f[j], asr[j], ss);
    float v = ss + sd;
    v = v > 0.f ? v : NEGS * v;
    float p = ok ? __expf(v) : 0.f;
    den += p;
#pragma unroll
    for (int j = 0; j < 8; ++j) acc[j] = fmaf(p, f[j], acc[j]);
  }
#pragma unroll
  for (int off = 8; off < 64; off <<= 1) {
    den += __shfl_xor(den, off);
#pragma unroll
    for (int j = 0; j < 8; ++j) acc[j] += __shfl_xor(acc[j], off);
  }
  // all 64 lanes now hold the node's full h1 slice for head chg:
  float inv = 1.f / den;
  float o[8];
#pragma unroll
  for (int j = 0; j < 8; ++j) {
    float v = acc[j] * inv + b1[chg * 8 + j];
    o[j] = v > 0.f ? v : (__expf(v) - 1.f);   // ELU in-register
  }
  // xw2 = h1 @ W2 in-wave: lane computes 2 output channels (slot*2, slot*2+1)
  const float4* wl = (const float4*)(W2p + lane * 16);
  float4 w0 = wl[0], w1 = wl[1], w2 = wl[2], w3 = wl[3];
  float p0, p1;
  p0 = o[0] * w0.x + o[1] * w0.z + o[2] * w1.x + o[3] * w1.z +
       o[4] * w2.x + o[5] * w2.z + o[6] * w3.x + o[7] * w3.z;
  p1 = o[0] * w0.y + o[1] * w0.w + o[2] * w1.y + o[3] * w1.w +
       o[4] * w2.y + o[5] * w2.w + o[6] * w3.y + o[7] * w3.w;
  // reduce across heads (chg = lane&7 -> strides 1,2,4)
  p0 += __shfl_xor(p0, 1); p0 += __shfl_xor(p0, 2); p0 += __shfl_xor(p0, 4);
  p1 += __shfl_xor(p1, 1); p1 += __shfl_xor(p1, 2); p1 += __shfl_xor(p1, 4);
  // attention-half dots for layer 2
  int c0i = slot * 2;
  float ssv = p0 * a2s[c0i] + p1 * a2s[c0i + 1];
  float sdv = p0 * a2d[c0i] + p1 * a2d[c0i + 1];
#pragma unroll
  for (int off = 8; off < 64; off <<= 1) {
    ssv += __shfl_xor(ssv, off);
    sdv += __shfl_xor(sdv, off);
  }
  if (chg == 0)
    ((unsigned*)xw2b)[(size_t)wid * 8 + slot] = packbf(p0, p1);
  if (lane == 0) { ssrc2[wid] = ssv; sdst2[wid] = sdv; }
}

// ---------------- layer-2 aggregate (bf16 payload) + log_softmax ------------
__global__ __launch_bounds__(256) void k_agg2(const int* __restrict__ rowptr,
                                              const int* __restrict__ col,
                                              const float* __restrict__ ssrc,
                                              const float* __restrict__ sdst,
                                              const unsigned short* __restrict__ xw2b,
                                              const float* __restrict__ b2,
                                              float* __restrict__ out, int Nn) {
  int wid = (blockIdx.x * 256 + threadIdx.x) >> 6;
  if (wid >= Nn) return;
  int lane = threadIdx.x & 63;
  int slot = lane >> 4, c = lane & 15;
  float sd = sdst[wid];
  int start = rowptr[wid], end = rowptr[wid + 1];
  float den = 0.f, acc = 0.f;
  int i = start + slot;
  for (; i + 4 < end; i += 8) {
    int s0 = col[i], s1 = col[i + 4];
    float w0 = bf2f(xw2b[(size_t)s0 * 16 + c]);
    float w1 = bf2f(xw2b[(size_t)s1 * 16 + c]);
    float v0 = ssrc[s0] + sd; v0 = v0 > 0.f ? v0 : NEGS * v0;
    float v1 = ssrc[s1] + sd; v1 = v1 > 0.f ? v1 : NEGS * v1;
    float p0 = __expf(v0), p1 = __expf(v1);
    den += p0 + p1;
    acc = fmaf(p0, w0, acc);
    acc = fmaf(p1, w1, acc);
  }
  if (i < end) {
    int s = col[i];
    float v = ssrc[s] + sd;
    v = v > 0.f ? v : NEGS * v;
    float p = __expf(v);
    den += p;
    acc = fmaf(p, bf2f(xw2b[(size_t)s * 16 + c]), acc);
  }
  den += __shfl_xor(den, 16);
  den += __shfl_xor(den, 32);
  acc += __shfl_xor(acc, 16);
  acc += __shfl_xor(acc, 32);
  float o = acc / den + b2[c];
  float mx = o;
#pragma unroll
  for (int off = 1; off < 16; off <<= 1) mx = fmaxf(mx, __shfl_xor(mx, off));
  float ex = __expf(o - mx);
  float ssum = ex;
#pragma unroll
  for (int off = 1; off < 16; off <<= 1) ssum += __shfl_xor(ssum, off);
  float r = o - mx - __logf(ssum);
  if (slot == 0) out[(size_t)wid * 16 + c] = r;
}

extern "C" void kernel_launch(void* const* d_in, const int* in_sizes, int n_in,
                              void* d_out, int out_size, void* d_ws, size_t ws_size,
                              hipStream_t stream) {
  const float* x      = (const float*)d_in[0];
  const int* ei       = (const int*)d_in[1];
  const float* W1     = (const float*)d_in[2];
  const float* a_src1 = (const float*)d_in[3];
  const float* a_dst1 = (const float*)d_in[4];
  const float* b1     = (const float*)d_in[5];
  const float* W2     = (const float*)d_in[6];
  const float* a_src2 = (const float*)d_in[7];
  const float* a_dst2 = (const float*)d_in[8];
  const float* b2     = (const float*)d_in[9];

  const int F    = in_sizes[2] / 64;   // 500
  const int Nn   = in_sizes[0] / F;    // 100000
  const int E    = in_sizes[1] / 2;    // 1600000
  const int Etot = E + Nn;
  const int nck  = (F + 63) >> 6;
  const int Kp   = nck * 64;
  const int NB   = (Nn + (1 << BSH) - 1) >> BSH;   // 196 (<=256)
  const int NT   = (E + TS - 1) / TS;              // 391 (<=512)
  const int WCB  = (Kp * 64 + 255) / 256;
  const int GB   = (Nn + 63) / 64;
  const int G1   = (GB + 2) / 3;
  const int G2   = G1;
  const int G3   = GB - G1 - G2;

  // ---- workspace layout (4-byte units) ----
  float* ws = (float*)d_ws;
  unsigned short* xwb = (unsigned short*)ws;          // Nn*64 bf16 (live thru agg1f)
  float* h1reg  = ws + (size_t)Nn * 32;               // Nn*64 region (pairs/xw2b)
  float* ssrc1  = h1reg + (size_t)Nn * 64;            // Nn*8 (unused)
  float* sdst1  = ssrc1 + (size_t)Nn * 8;             // Nn*8
  int* rowptr   = (int*)(sdst1 + (size_t)Nn * 8);     // Nn+1
  int* col      = rowptr + Nn + 1;                    // Etot
  unsigned short* Wb = (unsigned short*)(col + ((Etot + 7) & ~7));  // Kp*64
  int* hist     = (int*)(Wb + (size_t)Kp * 64);       // NT*NB
  int* off_rel  = hist + (size_t)NT * NB;             // NT*NB
  int* total    = off_rel + (size_t)NT * NB;          // NB
  float* W2p    = (float*)(total + 256);              // 1024 f32
  unsigned* pairs = (unsigned*)h1reg;                 // E u32 (dead after bcsr)
  // layer-2 buffers live in the h1 region (pairs dead; xwb stays live)
  unsigned short* xw2b = (unsigned short*)h1reg;      // Nn*16 bf16
  float* ssrc2  = h1reg + (size_t)Nn * 8;             // Nn
  float* sdst2  = ssrc2 + Nn;                         // Nn
  float* out2   = (float*)d_out;

  dim3 blk(256);

  // L1: wcvt || w2pack || thist
  k_A<<<dim3(WCB + 1 + NT), blk, 0, stream>>>(W1, Wb, F, Kp, ei, hist, E, NB,
                                              WCB, W2, W2p);
  // L2: bscan1 || gemm rows [0, G1)
  k_B1<<<dim3(NB + G1), blk, 0, stream>>>(hist, off_rel, total, NT, NB,
      x, Wb, xwb, a_dst1, sdst1, Nn, F, nck, 0);
  // L3: pscatter || gemm rows [G1, G1+G2)
  k_B2<<<dim3(NT + G2), blk, 0, stream>>>(ei, off_rel, total, pairs, E, NB, NT,
      x, Wb, xwb, a_dst1, sdst1, Nn, F, nck, G1);
  // L4: bcsr || gemm rows [G1+G2, GB)
  k_B3<<<dim3(NB + G3), blk, 0, stream>>>(pairs, total, rowptr, col, Nn, E, NB,
      x, Wb, xwb, a_dst1, sdst1, Nn, F, nck, G1 + G2);
  // L5: agg1 + fused gemm2/prep2
  k_agg1f<<<dim3((Nn * 64 + 255) / 256), blk, 0, stream>>>(
      rowptr, col, a_src1, sdst1, xwb, b1, W2p, a_src2, a_dst2,
      xw2b, ssrc2, sdst2, Nn);
  // L6: layer-2 aggregate + log_softmax
  k_agg2<<<dim3((Nn * 64 + 255) / 256), blk, 0, stream>>>(
      rowptr, col, ssrc2, sdst2, xw2b, b2, out2, Nn);
}

// Round 13
// 190.243 us; speedup vs baseline: 1.2584x; 1.0846x over previous
//
#include <hip/hip_runtime.h>
#include <hip/hip_bf16.h>
#include <math.h>

#define NEGS 0.2f
#define BSH 9                 // bucket shift: 512 nodes per bucket
#define TS 4096               // edges per partition tile

typedef __attribute__((ext_vector_type(8))) short bf16x8;
typedef __attribute__((ext_vector_type(8))) unsigned short u16x8;
typedef __attribute__((ext_vector_type(4))) float f32x4;

__device__ __forceinline__ unsigned short f2bf(float f) {
  __hip_bfloat16 h = __float2bfloat16(f);
  unsigned short u;
  __builtin_memcpy(&u, &h, 2);
  return u;
}
__device__ __forceinline__ float bf2f(unsigned short u) {
  return __uint_as_float((unsigned)u << 16);
}
__device__ __forceinline__ unsigned packbf(float lo, float hi) {
  return (unsigned)f2bf(lo) | ((unsigned)f2bf(hi) << 16);
}

// ---------------- device bodies (block-range fused) -------------------------

__device__ __forceinline__ void dev_wcvt(const float* __restrict__ W1,
                                         unsigned short* __restrict__ Wb,
                                         int K, int Kp, int blk) {
  int t = blk * 256 + threadIdx.x;
  if (t >= Kp * 64) return;
  int kg = t >> 6, c = t & 63;
  float f = (kg < K) ? W1[(size_t)kg * 64 + c] : 0.f;
  size_t off = ((size_t)((kg >> 5) * 4 + ((kg >> 3) & 3)) * 512) + c * 8 + (kg & 7);
  Wb[off] = f2bf(f);
}

// W2 -> lane-packed W2p[lane*16 + j*2 + c'] = W2[(chg*8+j)*16 + slot*2 + c']
__device__ __forceinline__ void dev_w2p(const float* __restrict__ W2,
                                        float* __restrict__ W2p) {
  int t = threadIdx.x;
#pragma unroll
  for (int u = 0; u < 4; ++u) {
    int i = u * 256 + t;        // 0..1023
    int lane = i >> 4, r = i & 15;
    int slot = lane >> 3, chg = lane & 7;
    int j = r >> 1, cp = r & 1;
    W2p[i] = W2[(chg * 8 + j) * 16 + slot * 2 + cp];
  }
}

__device__ __forceinline__ void dev_thist(const int* __restrict__ ei,
                                          int* __restrict__ hist,
                                          int E, int NB, int tile) {
  __shared__ int lh[256];
  const int t = threadIdx.x;
  lh[t] = 0;
  __syncthreads();
  const int e0 = tile * TS;
#pragma unroll
  for (int j = 0; j < TS / 256; ++j) {
    int e = e0 + j * 256 + t;
    if (e < E) atomicAdd(&lh[ei[E + e] >> BSH], 1);
  }
  __syncthreads();
  if (t < NB) hist[tile * NB + t] = lh[t];
}

__device__ __forceinline__ void dev_bscan1(const int* __restrict__ hist,
                                           int* __restrict__ off_rel,
                                           int* __restrict__ total,
                                           int NT, int NB, int b) {
  __shared__ int sh[256];
  const int t = threadIdx.x;
  int t0 = 2 * t, t1 = 2 * t + 1;
  int v0 = (t0 < NT) ? hist[t0 * NB + b] : 0;
  int v1 = (t1 < NT) ? hist[t1 * NB + b] : 0;
  int ps = v0 + v1;
  sh[t] = ps;
  __syncthreads();
  for (int off = 1; off < 256; off <<= 1) {
    int v = (t >= off) ? sh[t - off] : 0;
    __syncthreads();
    sh[t] += v;
    __syncthreads();
  }
  int excl = sh[t] - ps;
  if (t0 < NT) off_rel[t0 * NB + b] = excl;
  if (t1 < NT) off_rel[t1 * NB + b] = excl + v0;
  if (t == 255) total[b] = sh[255];
}

__device__ __forceinline__ void dev_pscatter(const int* __restrict__ ei,
                                             const int* __restrict__ off_rel,
                                             const int* __restrict__ total,
                                             unsigned* __restrict__ pairs,
                                             int E, int NB, int tile) {
  __shared__ int cur[256];
  __shared__ int sb[256];
  const int t = threadIdx.x;
  int v = (t < NB) ? total[t] : 0;
  sb[t] = v;
  __syncthreads();
  for (int off = 1; off < 256; off <<= 1) {
    int x = (t >= off) ? sb[t - off] : 0;
    __syncthreads();
    sb[t] += x;
    __syncthreads();
  }
  if (t < NB) cur[t] = (sb[t] - v) + off_rel[tile * NB + t];
  __syncthreads();
  const int e0 = tile * TS;
#pragma unroll
  for (int j = 0; j < TS / 256; ++j) {
    int e = e0 + j * 256 + t;
    if (e < E) {
      int s = ei[e], d = ei[E + e];
      int pos = atomicAdd(&cur[d >> BSH], 1);
      pairs[pos] = ((unsigned)(d & ((1 << BSH) - 1)) << 23) | (unsigned)s;
    }
  }
}

__device__ __forceinline__ void dev_bcsr(const unsigned* __restrict__ pairs,
                                         const int* __restrict__ total,
                                         int* __restrict__ rowptr,
                                         int* __restrict__ col,
                                         int Nn, int E, int NB, int b) {
  __shared__ int cnt[1 << BSH];
  __shared__ int cu[1 << BSH];
  __shared__ int sh[256];
  __shared__ int P0, P1;
  const int t = threadIdx.x;
  const int d0 = b << BSH;
  const int dn = min(1 << BSH, Nn - d0);
  {
    int v = (t < NB) ? total[t] : 0;
    sh[t] = v;
    __syncthreads();
    for (int off = 1; off < 256; off <<= 1) {
      int x = (t >= off) ? sh[t - off] : 0;
      __syncthreads();
      sh[t] += x;
      __syncthreads();
    }
    if (t == b) { P0 = sh[t] - v; P1 = sh[t]; }
    __syncthreads();
  }
  const int p0 = P0, p1 = P1;
  const int rpb = p0 + d0;
  cnt[2 * t] = (2 * t < dn) ? 1 : 0;
  cnt[2 * t + 1] = (2 * t + 1 < dn) ? 1 : 0;
  __syncthreads();
  for (int i = p0 + t; i < p1; i += 256) atomicAdd(&cnt[pairs[i] >> 23], 1);
  __syncthreads();
  int a0 = cnt[2 * t], a1 = cnt[2 * t + 1];
  int ps = a0 + a1;
  sh[t] = ps;
  __syncthreads();
  for (int off = 1; off < 256; off <<= 1) {
    int v = (t >= off) ? sh[t - off] : 0;
    __syncthreads();
    sh[t] += v;
    __syncthreads();
  }
  int excl = sh[t] - ps;
#pragma unroll
  for (int u = 0; u < 2; ++u) {
    int i = 2 * t + u;
    int ex = (u == 0) ? excl : excl + a0;
    if (i < dn) {
      rowptr[d0 + i] = rpb + ex;
      col[rpb + ex] = d0 + i;   // self-loop
      cu[i] = ex + 1;
    }
  }
  if (b == NB - 1 && t == 0) rowptr[Nn] = E + Nn;
  __syncthreads();
  for (int i = p0 + t; i < p1; i += 256) {
    unsigned p = pairs[i];
    int pos = atomicAdd(&cu[p >> 23], 1);
    col[rpb + pos] = (int)(p & 0x7fffffu);
  }
}

// GEMM1 slice (no LDS, depth-3 A prefetch) + fused sdst epilogue
__device__ __forceinline__ void dev_gemm(const float* __restrict__ A,
                                         const unsigned short* __restrict__ Wb,
                                         unsigned short* __restrict__ C,
                                         const float* __restrict__ a1d,
                                         float* __restrict__ sdst,
                                         int M, int K, int nck, int rowblk) {
  const int tid = threadIdx.x;
  const int lane = tid & 63;
  const int w = tid >> 6;
  const int r15 = lane & 15;
  const int kgrp = lane >> 4;
  const int bm = rowblk * 64;
  const int row = bm + w * 16 + r15;
  const float* Ar = A + (size_t)(row < M ? row : (M - 1)) * K;
  const int NIT = 2 * nck;
  const int ITV = (K >= 40) ? ((K - 40) / 32 + 1) : 0;   // vector-safe iters

  f32x4 acc[4] = {};

  auto loadA = [&](int it, float4& o0, float4& o1) {
    int k0 = it * 32 + kgrp * 8;
    if (it < ITV) {
      const float4* g = (const float4*)(Ar + k0);
      o0 = g[0]; o1 = g[1];
    } else {
      float tmp[8];
#pragma unroll
      for (int j = 0; j < 8; ++j) {
        int kk = k0 + j;
        tmp[j] = (kk < K) ? Ar[kk] : 0.f;
      }
      o0 = make_float4(tmp[0], tmp[1], tmp[2], tmp[3]);
      o1 = make_float4(tmp[4], tmp[5], tmp[6], tmp[7]);
    }
  };

  float4 c0, c1, d0, d1, e0, e1;
  loadA(0, c0, c1);
  if (NIT > 1) loadA(1, d0, d1);
  if (NIT > 2) loadA(2, e0, e1);
  for (int it = 0; it < NIT; ++it) {
    float4 f0, f1;
    if (it + 3 < NIT) loadA(it + 3, f0, f1);
    const unsigned short* bb = Wb + ((size_t)(it * 4 + kgrp) * 512) + r15 * 8;
    bf16x8 bf4[4];
#pragma unroll
    for (int nc = 0; nc < 4; ++nc)
      bf4[nc] = *(const bf16x8*)(bb + nc * 128);
    unsigned pk[4] = { packbf(c0.x, c0.y), packbf(c0.z, c0.w),
                       packbf(c1.x, c1.y), packbf(c1.z, c1.w) };
    bf16x8 af = *(bf16x8*)pk;
#pragma unroll
    for (int nc = 0; nc < 4; ++nc)
      acc[nc] = __builtin_amdgcn_mfma_f32_16x16x32_bf16(af, bf4[nc], acc[nc], 0, 0, 0);
    c0 = d0; c1 = d1;
    d0 = e0; d1 = e1;
    e0 = f0; e1 = f1;
  }
  // epilogue: bf16 C write + fused sdst dot (a_dst half only)
  float dv[4];
#pragma unroll
  for (int nc = 0; nc < 4; ++nc) dv[nc] = a1d[nc * 16 + r15];
#pragma unroll
  for (int j = 0; j < 4; ++j) {
    int grow = bm + w * 16 + kgrp * 4 + j;
    bool liv = grow < M;
#pragma unroll
    for (int nc = 0; nc < 4; ++nc) {
      if (liv) C[(size_t)grow * 64 + nc * 16 + r15] = f2bf(acc[nc][j]);
      float sd = acc[nc][j] * dv[nc];
      sd += __shfl_xor(sd, 1); sd += __shfl_xor(sd, 2); sd += __shfl_xor(sd, 4);
      if ((r15 & 7) == 0 && liv)
        sdst[grow * 8 + nc * 2 + (r15 >> 3)] = sd;
    }
  }
}

// ---------------- fused launch wrappers -------------------------------------
__global__ __launch_bounds__(256) void k_A(const float* __restrict__ W1,
                                           unsigned short* __restrict__ Wb,
                                           int K, int Kp,
                                           const int* __restrict__ ei,
                                           int* __restrict__ hist,
                                           int E, int NB, int WCB,
                                           const float* __restrict__ W2,
                                           float* __restrict__ W2p) {
  int b = blockIdx.x;
  if (b < WCB) dev_wcvt(W1, Wb, K, Kp, b);
  else if (b == WCB) dev_w2p(W2, W2p);
  else dev_thist(ei, hist, E, NB, b - WCB - 1);
}

__global__ __launch_bounds__(256) void k_B1(const int* __restrict__ hist,
                                            int* __restrict__ off_rel,
                                            int* __restrict__ total,
                                            int NT, int NB,
                                            const float* __restrict__ A,
                                            const unsigned short* __restrict__ Wb,
                                            unsigned short* __restrict__ C,
                                            const float* __restrict__ a1d,
                                            float* __restrict__ sdst,
                                            int M, int K, int nck, int R0) {
  int b = blockIdx.x;
  if (b < NB) dev_bscan1(hist, off_rel, total, NT, NB, b);
  else dev_gemm(A, Wb, C, a1d, sdst, M, K, nck, b - NB + R0);
}

__global__ __launch_bounds__(256) void k_B2(const int* __restrict__ ei,
                                            const int* __restrict__ off_rel,
                                            const int* __restrict__ total,
                                            unsigned* __restrict__ pairs,
                                            int E, int NB, int NT,
                                            const float* __restrict__ A,
                                            const unsigned short* __restrict__ Wb,
                                            unsigned short* __restrict__ C,
                                            const float* __restrict__ a1d,
                                            float* __restrict__ sdst,
                                            int M, int K, int nck, int R0) {
  int b = blockIdx.x;
  if (b < NT) dev_pscatter(ei, off_rel, total, pairs, E, NB, b);
  else dev_gemm(A, Wb, C, a1d, sdst, M, K, nck, b - NT + R0);
}

__global__ __launch_bounds__(256) void k_B3(const unsigned* __restrict__ pairs,
                                            const int* __restrict__ total,
                                            int* __restrict__ rowptr,
                                            int* __restrict__ col,
                                            int Nn, int E, int NB,
                                            const float* __restrict__ A,
                                            const unsigned short* __restrict__ Wb,
                                            unsigned short* __restrict__ C,
                                            const float* __restrict__ a1d,
                                            float* __restrict__ sdst,
                                            int M, int K, int nck, int R0) {
  int b = blockIdx.x;
  if (b < NB) dev_bcsr(pairs, total, rowptr, col, Nn, E, NB, b);
  else dev_gemm(A, Wb, C, a1d, sdst, M, K, nck, b - NB + R0);
}

// ------- layer-1 aggregate + FUSED gemm2/prep2: one wave per node -----------
__global__ __launch_bounds__(256) void k_agg1f(const int* __restrict__ rowptr,
                                               const int* __restrict__ col,
                                               const float* __restrict__ a1s,
                                               const float* __restrict__ sdst,
                                               const unsigned short* __restrict__ xwb,
                                               const float* __restrict__ b1,
                                               const float* __restrict__ W2p,
                                               const float* __restrict__ a2s,
                                               const float* __restrict__ a2d,
                                               unsigned short* __restrict__ xw2b,
                                               float* __restrict__ ssrc2,
                                               float* __restrict__ sdst2, int Nn) {
  int wid = (blockIdx.x * 256 + threadIdx.x) >> 6;
  if (wid >= Nn) return;
  int lane = threadIdx.x & 63;
  int slot = lane >> 3;     // edge slot 0..7 / output ch pair
  int chg = lane & 7;       // head 0..7
  float asr[8];
#pragma unroll
  for (int j = 0; j < 8; ++j) asr[j] = a1s[chg * 8 + j];
  float sd = sdst[wid * 8 + chg];
  int start = rowptr[wid], end = rowptr[wid + 1];
  float den = 0.f;
  float acc[8] = {};
  for (int it = start; it < end; it += 8) {
    int idx = it + slot;
    bool ok = idx < end;
    int s = col[ok ? idx : start];
    u16x8 pv = *(const u16x8*)(xwb + (size_t)s * 64 + chg * 8);
    float f[8];
#pragma unroll
    for (int j = 0; j < 8; ++j) f[j] = bf2f(pv[j]);
    float ss = 0.f;
#pragma unroll
    for (int j = 0; j < 8; ++j) ss = fmaf(f[j], asr[j], ss);
    float v = ss + sd;
    v = v > 0.f ? v : NEGS * v;
    float p = ok ? __expf(v) : 0.f;
    den += p;
#pragma unroll
    for (int j = 0; j < 8; ++j) acc[j] = fmaf(p, f[j], acc[j]);
  }
#pragma unroll
  for (int off = 8; off < 64; off <<= 1) {
    den += __shfl_xor(den, off);
#pragma unroll
    for (int j = 0; j < 8; ++j) acc[j] += __shfl_xor(acc[j], off);
  }
  // all 64 lanes now hold the node's full h1 slice for head chg:
  float inv = 1.f / den;
  float o[8];
#pragma unroll
  for (int j = 0; j < 8; ++j) {
    float v = acc[j] * inv + b1[chg * 8 + j];
    o[j] = v > 0.f ? v : (__expf(v) - 1.f);   // ELU in-register
  }
  // xw2 = h1 @ W2 in-wave: lane computes 2 output channels (slot*2, slot*2+1)
  const float4* wl = (const float4*)(W2p + lane * 16);
  float4 w0 = wl[0], w1 = wl[1], w2 = wl[2], w3 = wl[3];
  float p0, p1;
  p0 = o[0] * w0.x + o[1] * w0.z + o[2] * w1.x + o[3] * w1.z +
       o[4] * w2.x + o[5] * w2.z + o[6] * w3.x + o[7] * w3.z;
  p1 = o[0] * w0.y + o[1] * w0.w + o[2] * w1.y + o[3] * w1.w +
       o[4] * w2.y + o[5] * w2.w + o[6] * w3.y + o[7] * w3.w;
  p0 += __shfl_xor(p0, 1); p0 += __shfl_xor(p0, 2); p0 += __shfl_xor(p0, 4);
  p1 += __shfl_xor(p1, 1); p1 += __shfl_xor(p1, 2); p1 += __shfl_xor(p1, 4);
  int c0i = slot * 2;
  float ssv = p0 * a2s[c0i] + p1 * a2s[c0i + 1];
  float sdv = p0 * a2d[c0i] + p1 * a2d[c0i + 1];
#pragma unroll
  for (int off = 8; off < 64; off <<= 1) {
    ssv += __shfl_xor(ssv, off);
    sdv += __shfl_xor(sdv, off);
  }
  if (chg == 0)
    ((unsigned*)xw2b)[(size_t)wid * 8 + slot] = packbf(p0, p1);
  if (lane == 0) { ssrc2[wid] = ssv; sdst2[wid] = sdv; }
}

// ---- layer-2 aggregate: lane = slot(16) x cq(4), 16 edges in flight --------
__global__ __launch_bounds__(256) void k_agg2(const int* __restrict__ rowptr,
                                              const int* __restrict__ col,
                                              const float* __restrict__ ssrc,
                                              const float* __restrict__ sdst,
                                              const unsigned short* __restrict__ xw2b,
                                              const float* __restrict__ b2,
                                              float* __restrict__ out, int Nn) {
  int wid = (blockIdx.x * 256 + threadIdx.x) >> 6;
  if (wid >= Nn) return;
  int lane = threadIdx.x & 63;
  int slot = lane >> 2;     // 0..15 edge slots
  int cq = lane & 3;        // channel quad
  float sd = sdst[wid];
  int start = rowptr[wid], end = rowptr[wid + 1];
  float den = 0.f;
  float acc[4] = {};
  for (int i = start + slot; i < end; i += 16) {
    int s = col[i];
    ushort4 pv = *(const ushort4*)(xw2b + (size_t)s * 16 + cq * 4);  // 8B
    float v = ssrc[s] + sd;
    v = v > 0.f ? v : NEGS * v;
    float p = __expf(v);
    den += p;
    acc[0] = fmaf(p, bf2f(pv.x), acc[0]);
    acc[1] = fmaf(p, bf2f(pv.y), acc[1]);
    acc[2] = fmaf(p, bf2f(pv.z), acc[2]);
    acc[3] = fmaf(p, bf2f(pv.w), acc[3]);
  }
#pragma unroll
  for (int off = 4; off < 64; off <<= 1) {
    den += __shfl_xor(den, off);
#pragma unroll
    for (int j = 0; j < 4; ++j) acc[j] += __shfl_xor(acc[j], off);
  }
  float inv = 1.f / den;
  float o[4];
#pragma unroll
  for (int j = 0; j < 4; ++j) o[j] = acc[j] * inv + b2[cq * 4 + j];
  float mx = fmaxf(fmaxf(o[0], o[1]), fmaxf(o[2], o[3]));
  mx = fmaxf(mx, __shfl_xor(mx, 1));
  mx = fmaxf(mx, __shfl_xor(mx, 2));
  float es = 0.f;
#pragma unroll
  for (int j = 0; j < 4; ++j) es += __expf(o[j] - mx);
  es += __shfl_xor(es, 1);
  es += __shfl_xor(es, 2);
  float ls = __logf(es);
  if (slot == 0) {
    float4 r = make_float4(o[0] - mx - ls, o[1] - mx - ls,
                           o[2] - mx - ls, o[3] - mx - ls);
    *(float4*)(out + (size_t)wid * 16 + cq * 4) = r;
  }
}

extern "C" void kernel_launch(void* const* d_in, const int* in_sizes, int n_in,
                              void* d_out, int out_size, void* d_ws, size_t ws_size,
                              hipStream_t stream) {
  const float* x      = (const float*)d_in[0];
  const int* ei       = (const int*)d_in[1];
  const float* W1     = (const float*)d_in[2];
  const float* a_src1 = (const float*)d_in[3];
  const float* a_dst1 = (const float*)d_in[4];
  const float* b1     = (const float*)d_in[5];
  const float* W2     = (const float*)d_in[6];
  const float* a_src2 = (const float*)d_in[7];
  const float* a_dst2 = (const float*)d_in[8];
  const float* b2     = (const float*)d_in[9];

  const int F    = in_sizes[2] / 64;   // 500
  const int Nn   = in_sizes[0] / F;    // 100000
  const int E    = in_sizes[1] / 2;    // 1600000
  const int Etot = E + Nn;
  const int nck  = (F + 63) >> 6;
  const int Kp   = nck * 64;
  const int NB   = (Nn + (1 << BSH) - 1) >> BSH;   // 196 (<=256)
  const int NT   = (E + TS - 1) / TS;              // 391 (<=512)
  const int WCB  = (Kp * 64 + 255) / 256;
  const int GB   = (Nn + 63) / 64;
  const int G1   = (GB + 2) / 3;
  const int G2   = G1;
  const int G3   = GB - G1 - G2;

  // ---- workspace layout (4-byte units) ----
  float* ws = (float*)d_ws;
  unsigned short* xwb = (unsigned short*)ws;          // Nn*64 bf16 (live thru agg1f)
  float* h1reg  = ws + (size_t)Nn * 32;               // Nn*64 region (pairs/xw2b)
  float* ssrc1  = h1reg + (size_t)Nn * 64;            // Nn*8 (unused)
  float* sdst1  = ssrc1 + (size_t)Nn * 8;             // Nn*8
  int* rowptr   = (int*)(sdst1 + (size_t)Nn * 8);     // Nn+1
  int* col      = rowptr + Nn + 1;                    // Etot
  unsigned short* Wb = (unsigned short*)(col + ((Etot + 7) & ~7));  // Kp*64
  int* hist     = (int*)(Wb + (size_t)Kp * 64);       // NT*NB
  int* off_rel  = hist + (size_t)NT * NB;             // NT*NB
  int* total    = off_rel + (size_t)NT * NB;          // NB
  float* W2p    = (float*)(total + 256);              // 1024 f32
  unsigned* pairs = (unsigned*)h1reg;                 // E u32 (dead after bcsr)
  // layer-2 buffers live in the h1 region (pairs dead; xwb stays live)
  unsigned short* xw2b = (unsigned short*)h1reg;      // Nn*16 bf16
  float* ssrc2  = h1reg + (size_t)Nn * 8;             // Nn
  float* sdst2  = ssrc2 + Nn;                         // Nn
  float* out2   = (float*)d_out;

  dim3 blk(256);

  // L1: wcvt || w2pack || thist
  k_A<<<dim3(WCB + 1 + NT), blk, 0, stream>>>(W1, Wb, F, Kp, ei, hist, E, NB,
                                              WCB, W2, W2p);
  // L2: bscan1 || gemm rows [0, G1)
  k_B1<<<dim3(NB + G1), blk, 0, stream>>>(hist, off_rel, total, NT, NB,
      x, Wb, xwb, a_dst1, sdst1, Nn, F, nck, 0);
  // L3: pscatter || gemm rows [G1, G1+G2)
  k_B2<<<dim3(NT + G2), blk, 0, stream>>>(ei, off_rel, total, pairs, E, NB, NT,
      x, Wb, xwb, a_dst1, sdst1, Nn, F, nck, G1);
  // L4: bcsr || gemm rows [G1+G2, GB)
  k_B3<<<dim3(NB + G3), blk, 0, stream>>>(pairs, total, rowptr, col, Nn, E, NB,
      x, Wb, xwb, a_dst1, sdst1, Nn, F, nck, G1 + G2);
  // L5: agg1 + fused gemm2/prep2
  k_agg1f<<<dim3((Nn * 64 + 255) / 256), blk, 0, stream>>>(
      rowptr, col, a_src1, sdst1, xwb, b1, W2p, a_src2, a_dst2,
      xw2b, ssrc2, sdst2, Nn);
  // L6: layer-2 aggregate + log_softmax
  k_agg2<<<dim3((Nn * 64 + 255) / 256), blk, 0, stream>>>(
      rowptr, col, ssrc2, sdst2, xw2b, b2, out2, Nn);
}